// Round 8
// baseline (616.211 us; speedup 1.0000x reference)
//
#include <hip/hip_runtime.h>
#include <hip/hip_bf16.h>
#include <math.h>

// Problem constants (from reference setup_inputs)
#define NNODES 100000
#define INIT_F 100
#define GC1_F  150
#define D_F    200
#define CCH    200
#define BB     128
#define NA_    8
#define EDG    500000
#define NCL    16

#define MROWS  100032   // 1563 * 64, padded row count for MFMA A operands
#define MT_    (MROWS/64)   // 1563 row stripes

// bf16 K-padded pitches (elements)
#define KPE    104      // emb_h pitch: 100 -> 104 (13 lanes * 8) -- gather1 input
#define KP1    128      // layer1 GEMM K: 100 -> 128 (Z1 pitch)
#define KP2    160      // layer2 input features: 150 -> 160
#define KPP    224      // head features: 200 -> 224
#define FCK    40000    // fc K

// bucketed CSR build
#define NPB    256                       // nodes per bucket
#define NBUK   ((NNODES + NPB - 1)/NPB)  // 391
#define BCAP   4096                      // slots per bucket (expected 2560, +30 sigma)

// head hi/lo layout strides (elements)
#define ALO ((long)128*KPP)      // A-side: [slot][2][128][KPP]; lo = hi + ALO
#define BLO ((long)256*KPP)      // B-side: [mat][2][256][KPP];  lo = hi + BLO

typedef __attribute__((ext_vector_type(8))) __bf16 bf16x8;
typedef __attribute__((ext_vector_type(4))) float  f32x4;

__device__ __forceinline__ float fast_tanh(float z){
  // tanh(z) = 1 - 2/(exp(2z)+1); v_exp + v_rcp, ~1e-6 rel.
  float ex = __expf(2.f*z);
  return 1.f - 2.f/(ex + 1.f);
}

// ---------------- bucketed CSR build ----------------

__global__ __launch_bounds__(256) void bucket_a_k(
    const int* __restrict__ ei, const int* __restrict__ erel,
    int* __restrict__ bcur, int2* __restrict__ blist)
{
  __shared__ int hist[NBUK];
  int t = threadIdx.x;
  for (int i = t; i < NBUK; i += 256) hist[i] = 0;
  __syncthreads();
  int e0 = blockIdx.x*1024;
  int rr[4], cc[4], pl[4], rkA[4], rkB[4];
  #pragma unroll
  for (int i = 0; i < 4; i++){
    int e = e0 + i*256 + t;
    bool ok = e < EDG;
    rr[i] = ok ? ei[e]       : -1;
    cc[i] = ok ? ei[EDG + e] : 0;
    pl[i] = (ok ? erel[e] : 0) << 17;
    if (ok){
      rkA[i] = atomicAdd(&hist[rr[i] >> 8], 1);
      rkB[i] = atomicAdd(&hist[cc[i] >> 8], 1);
    }
  }
  __syncthreads();
  for (int i = t; i < NBUK; i += 256){
    int c = hist[i];
    hist[i] = c ? atomicAdd(&bcur[i], c) : 0;
  }
  __syncthreads();
  #pragma unroll
  for (int i = 0; i < 4; i++){
    if (rr[i] < 0) continue;
    int bA = rr[i] >> 8, bB = cc[i] >> 8;
    int sA = hist[bA] + rkA[i];
    int sB = hist[bB] + rkB[i];
    if (sA < BCAP) blist[(long)bA*BCAP + sA] = make_int2(rr[i], cc[i] | pl[i]);
    if (sB < BCAP) blist[(long)bB*BCAP + sB] = make_int2(cc[i], rr[i] | pl[i]);
  }
}

__global__ __launch_bounds__(256) void bucket_b_k(
    const int2* __restrict__ blist, const int* __restrict__ bcur,
    unsigned* __restrict__ adjW, int* __restrict__ start_, int* __restrict__ deg_)
{
  __shared__ int cnt[NPB];
  __shared__ int sc[NPB];
  int b = blockIdx.x, t = threadIdx.x;
  cnt[t] = 0;
  __syncthreads();
  int n = min(bcur[b], BCAP);
  const int2* bl = blist + (long)b*BCAP;
  for (int i = t; i < n; i += 256) atomicAdd(&cnt[bl[i].x & (NPB-1)], 1);
  __syncthreads();
  int v = cnt[t]; sc[t] = v; __syncthreads();
  for (int off = 1; off < NPB; off <<= 1){
    int x = (t >= off) ? sc[t-off] : 0;
    __syncthreads();
    sc[t] += x; __syncthreads();
  }
  int excl = sc[t] - v;
  int node = b*NPB + t;
  if (node < NNODES){ start_[node] = b*BCAP + excl; deg_[node] = v; }
  cnt[t] = excl;
  __syncthreads();
  for (int i = t; i < n; i += 256){
    int2 rec = bl[i];
    int s = atomicAdd(&cnt[rec.x & (NPB-1)], 1);
    adjW[(long)b*BCAP + s] = (unsigned)rec.y;
  }
}

// ---------------- bf16 pre-GEMM gather, neighbor-parallel lane groups ----------------
// adjW entry: u | (rel << 17)  (u < 2^17, rel < 2^8)

template<int G, int LPG, int PIN, int POUT>
__global__ __launch_bounds__(256) void gather_g(
    const __bf16* __restrict__ X, const int* __restrict__ start,
    const int* __restrict__ degv, const unsigned* __restrict__ adjW,
    const float* __restrict__ alpha, __bf16* __restrict__ Z)
{
  int wave = threadIdx.x >> 6;
  int lane = threadIdx.x & 63;
  int v = blockIdx.x*4 + wave;
  if (v >= NNODES) return;
  int grp = lane / LPG;          // group id (>=G means idle lane)
  int li  = lane - grp*LPG;      // lane within group
  bool act = grp < G;
  int s = start[v], e = s + degv[v];
  float acc[8] = {};
  for (int jb = s; jb < e; jb += 4*G){
    int   u[4];
    float wt[4];
    #pragma unroll
    for (int q = 0; q < 4; q++){
      int j = jb + grp + q*G;
      u[q] = 0; wt[q] = 0.f;
      if (act && j < e){ unsigned pr = adjW[j]; u[q] = pr & 0x1FFFF; wt[q] = alpha[pr >> 17]; }
    }
    bf16x8 rows[4];
    #pragma unroll
    for (int q = 0; q < 4; q++)
      rows[q] = *(const bf16x8*)(X + (long)u[q]*PIN + li*8);
    #pragma unroll
    for (int q = 0; q < 4; q++)
      #pragma unroll
      for (int i = 0; i < 8; i++)
        acc[i] += wt[q]*(float)rows[q][i];
  }
  #pragma unroll
  for (int g = 1; g < G; g++){
    #pragma unroll
    for (int i = 0; i < 8; i++)
      acc[i] += __shfl(acc[i], lane + g*LPG, 64);
  }
  if (lane < LPG){
    bf16x8 o;
    #pragma unroll
    for (int i = 0; i < 8; i++) o[i] = (__bf16)acc[i];
    *(bf16x8*)(Z + (long)v*POUT + lane*8) = o;
  } else if (lane < POUT/8){
    bf16x8 o = {};
    *(bf16x8*)(Z + (long)v*POUT + lane*8) = o;
  }
}

// ---------------- GCN MFMA GEMM with fused bias+bn+tanh, bf16 out ----------------
// 64x64 tiles + XCD swizzle + load-all-then-compute, with a
// sched_barrier(0) fence between the load batch and the MFMA batch.
// Round-7 showed the scheduler silently re-interleaves the batch back to
// VGPR=32 / ~2 loads in flight; the fence forces all NK*5 loads live
// (~130 VGPR) -> ~25 outstanding loads/wave, cp.async-style progressive
// vmcnt drains before each MFMA.

template<int KP, int PHO, int NTILE>
__global__ __launch_bounds__(256, 2) void mfma_gcn(
    const __bf16* __restrict__ A, const __bf16* __restrict__ Bt,
    __bf16* __restrict__ C,
    const float* __restrict__ gb, const float* __restrict__ bng,
    const float* __restrict__ bnb, int M, int N)
{
  constexpr int NK = KP/32;
  int id = blockIdx.x;
  int x = id & 7, j = id >> 3;
  int stripe = x + 8*(j / NTILE);
  int nt = j - (j / NTILE)*NTILE;
  if (stripe >= MT_) return;
  int w = threadIdx.x >> 6, l = threadIdx.x & 63;
  int m0 = stripe*64 + w*16;
  int n0 = nt*64;
  int ml = l & 15, kq = l >> 4;
  const __bf16* Ap = A  + (long)(m0 + ml)*KP + kq*8;
  const __bf16* Bp = Bt + (long)(n0 + ml)*KP + kq*8;
  bf16x8 a[NK];
  bf16x8 b[NK][4];
  // issue in consumption order: a[k], b[k][0..3]
  #pragma unroll
  for (int k = 0; k < NK; k++){
    a[k] = *(const bf16x8*)(Ap + k*32);
    #pragma unroll
    for (int t = 0; t < 4; t++)
      b[k][t] = *(const bf16x8*)(Bp + (long)t*16*KP + k*32);
  }
  __builtin_amdgcn_sched_barrier(0);   // fence: loads may not sink past here
  f32x4 acc[4] = {};
  #pragma unroll
  for (int k = 0; k < NK; k++)
    #pragma unroll
    for (int t = 0; t < 4; t++)
      acc[t] = __builtin_amdgcn_mfma_f32_16x16x32_bf16(a[k], b[k][t], acc[t], 0, 0, 0);
  const float inv = rsqrtf(1.0f + 1e-5f);
  int mr = m0 + kq*4;
  #pragma unroll
  for (int t = 0; t < 4; t++){
    int gn = n0 + t*16 + ml;
    if (gn >= PHO) continue;
    bool real = gn < N;
    float gbb = real ? gb[gn] : 0.f;
    float sc  = real ? bng[gn]*inv : 0.f;
    float bb_ = real ? bnb[gn] : 0.f;
    #pragma unroll
    for (int r = 0; r < 4; r++){
      int gm = mr + r;
      if (gm < M){
        float xg = real ? fast_tanh((acc[t][r] + gbb)*sc + bb_) : 0.f;
        C[(long)gm*PHO + gn] = (__bf16)xg;
      }
    }
  }
}

// ---------------- bf16 MFMA GEMM, fp32 out (pred) ----------------

template<int KP, int ACT, int WPB>
__global__ __launch_bounds__(WPB*64) void mfma_gemm(
    const __bf16* __restrict__ A, const __bf16* __restrict__ Bt,
    float* __restrict__ C, long ldc, int M, int N)
{
  int w = threadIdx.x >> 6, l = threadIdx.x & 63;
  int m0 = blockIdx.y*(WPB*16) + w*16;
  int n0 = blockIdx.x*64;
  int ml = l & 15, kq = l >> 4;
  const __bf16* Ap = A  + (long)(m0 + ml)*KP + kq*8;
  const __bf16* Bp = Bt + (long)(n0 + ml)*KP + kq*8;
  f32x4 acc[4] = {};
  #pragma unroll
  for (int k0 = 0; k0 < KP; k0 += 32){
    bf16x8 a = *(const bf16x8*)(Ap + k0);
    #pragma unroll
    for (int t = 0; t < 4; t++){
      bf16x8 b = *(const bf16x8*)(Bp + (long)t*16*KP + k0);
      acc[t] = __builtin_amdgcn_mfma_f32_16x16x32_bf16(a, b, acc[t], 0, 0, 0);
    }
  }
  int mr = m0 + kq*4;
  #pragma unroll
  for (int t = 0; t < 4; t++){
    int gn = n0 + t*16 + ml;
    if (gn >= N) continue;
    #pragma unroll
    for (int r = 0; r < 4; r++){
      int gm = mr + r;
      if (gm < M){
        float x = acc[t][r];
        if (ACT == 2) x = 1.f/(1.f + __expf(-x));
        C[(long)gm*ldc + gn] = x;
      }
    }
  }
}

// ---------------- fc MFMA: split-K, atomic accumulate ----------------

__global__ __launch_bounds__(256) void mfma_fc_k(
    const __bf16* __restrict__ A, const __bf16* __restrict__ Bt,
    float* __restrict__ C, int M, int N, int klen)
{
  int w = threadIdx.x >> 6, l = threadIdx.x & 63;
  int m0 = blockIdx.y*64 + w*16;
  int n0 = blockIdx.x*128;
  long kb = (long)blockIdx.z * klen;
  int ml = l & 15, kq = l >> 4;
  const __bf16* Ap = A  + (long)(m0 + ml)*FCK + kb + kq*8;
  const __bf16* Bp = Bt + (long)(n0 + ml)*FCK + kb + kq*8;
  f32x4 acc[2][4] = {};
  #pragma unroll 2
  for (int k0 = 0; k0 < klen; k0 += 32){
    bf16x8 a = *(const bf16x8*)(Ap + k0);
    #pragma unroll
    for (int c = 0; c < 2; c++)
      #pragma unroll
      for (int t = 0; t < 4; t++){
        bf16x8 b = *(const bf16x8*)(Bp + (long)(c*64 + t*16)*FCK + k0);
        acc[c][t] = __builtin_amdgcn_mfma_f32_16x16x32_bf16(a, b, acc[c][t], 0, 0, 0);
      }
  }
  int mr = m0 + kq*4;
  #pragma unroll
  for (int c = 0; c < 2; c++)
    #pragma unroll
    for (int t = 0; t < 4; t++){
      int gn = n0 + c*64 + t*16 + ml;
      if (gn >= N) continue;
      #pragma unroll
      for (int r = 0; r < 4; r++){
        int gm = mr + r;
        if (gm < M) atomicAdd(&C[(long)gm*N + gn], acc[c][t][r]);
      }
    }
}

// ---------------- head MFMA: direct-load hi/lo bf16 split GEMM ----------------

template<int NPROD, int COMBINE, bool SPLITOUT>
__global__ __launch_bounds__(256) void mfma_head_k(
    const __bf16* __restrict__ A0, const __bf16* __restrict__ B0,
    const __bf16* __restrict__ A1, const __bf16* __restrict__ B1,
    const float* __restrict__ bias0, const float* __restrict__ bias1,
    float* __restrict__ outF, __bf16* __restrict__ outS,
    int ldc, int N)
{
  int w = threadIdx.x >> 6, l = threadIdx.x & 63;
  int m0 = blockIdx.y*64 + w*16;
  int n0 = blockIdx.x*64;
  int ml = l & 15, kq = l >> 4;
  long aoff = (long)(m0 + ml)*KPP + kq*8;
  long boff = (long)(n0 + ml)*KPP + kq*8;
  f32x4 accA[4] = {}, accB[4] = {};
  #pragma unroll
  for (int k0 = 0; k0 < KPP; k0 += 32){
    bf16x8 ah = *(const bf16x8*)(A0 + aoff + k0);
    bf16x8 al = *(const bf16x8*)(A0 + ALO + aoff + k0);
    #pragma unroll
    for (int t = 0; t < 4; t++){
      bf16x8 bh = *(const bf16x8*)(B0 + boff + (long)t*16*KPP + k0);
      bf16x8 bl = *(const bf16x8*)(B0 + BLO + boff + (long)t*16*KPP + k0);
      accA[t] = __builtin_amdgcn_mfma_f32_16x16x32_bf16(ah, bh, accA[t], 0, 0, 0);
      accA[t] = __builtin_amdgcn_mfma_f32_16x16x32_bf16(al, bh, accA[t], 0, 0, 0);
      accA[t] = __builtin_amdgcn_mfma_f32_16x16x32_bf16(ah, bl, accA[t], 0, 0, 0);
    }
    if constexpr (NPROD == 2){
      bf16x8 ch = *(const bf16x8*)(A1 + aoff + k0);
      bf16x8 cl = *(const bf16x8*)(A1 + ALO + aoff + k0);
      #pragma unroll
      for (int t = 0; t < 4; t++){
        bf16x8 bh = *(const bf16x8*)(B1 + boff + (long)t*16*KPP + k0);
        bf16x8 bl = *(const bf16x8*)(B1 + BLO + boff + (long)t*16*KPP + k0);
        accB[t] = __builtin_amdgcn_mfma_f32_16x16x32_bf16(ch, bh, accB[t], 0, 0, 0);
        accB[t] = __builtin_amdgcn_mfma_f32_16x16x32_bf16(cl, bh, accB[t], 0, 0, 0);
        accB[t] = __builtin_amdgcn_mfma_f32_16x16x32_bf16(ch, bl, accB[t], 0, 0, 0);
      }
    }
  }
  int mr = m0 + kq*4;
  #pragma unroll
  for (int t = 0; t < 4; t++){
    int gn = n0 + t*16 + ml;
    if (SPLITOUT){ if (gn >= KPP) continue; }
    else         { if (gn >= N)   continue; }
    bool real = gn < N;
    float bb0 = real ? bias0[gn] : 0.f;
    float bb1 = (COMBINE == 0 && real) ? bias1[gn] : 0.f;
    #pragma unroll
    for (int r = 0; r < 4; r++){
      int gm = mr + r;
      float x;
      if (COMBINE == 0){
        float xa = accA[t][r] + bb0; xa = (xa >= 0.f) ? xa : 0.01f*xa;
        float xb = accB[t][r] + bb1; xb = (xb >= 0.f) ? xb : 0.01f*xb;
        x = xa + xb;
      } else if (COMBINE == 1){
        x = accA[t][r] + accB[t][r] + bb0;
        x = (x >= 0.f) ? x : 0.01f*x;
      } else {
        x = accA[t][r] + bb0;
        x = 1.f/(1.f + __expf(-x));
      }
      if (!real) x = 0.f;
      if (SPLITOUT){
        __bf16 h = (__bf16)x;
        outS[(long)gm*KPP + gn] = h;
        outS[ALO + (long)gm*KPP + gn] = (__bf16)(x - (float)h);
      } else {
        outF[(long)gm*ldc + gn] = x;
      }
    }
  }
}

// ---------------- conversion helpers ----------------

__global__ __launch_bounds__(256) void emb_to_bf16_k(const float* __restrict__ src,
                                                     __bf16* __restrict__ dst){
  int lane = threadIdx.x & 63;
  int half = lane >> 5, l = lane & 31;
  long r = (long)blockIdx.x*8 + (threadIdx.x >> 6)*2 + half;
  if (r >= NNODES || l >= 26) return;
  float4 v = make_float4(0.f, 0.f, 0.f, 0.f);
  if (l < 25) v = *(const float4*)(src + r*INIT_F + l*4);
  __bf16 o[4] __attribute__((aligned(8))) =
      {(__bf16)v.x, (__bf16)v.y, (__bf16)v.z, (__bf16)v.w};
  *reinterpret_cast<uint2*>(dst + r*KPE + l*4) = *reinterpret_cast<const uint2*>(o);
}

__global__ void transpose_w_k(const float* __restrict__ W, __bf16* __restrict__ Bt,
                              int K, int N, int Kp){
  int n = blockIdx.x;
  for (int k = threadIdx.x; k < Kp; k += blockDim.x){
    float v = (k < K && n < N) ? W[(long)k*N + n] : 0.f;
    Bt[(long)n*Kp + k] = (__bf16)v;
  }
}

__global__ void f32_to_bf16_flat_k(const float4* __restrict__ src,
                                   __bf16* __restrict__ dst, long n4){
  long i = (long)blockIdx.x*256 + threadIdx.x;
  if (i >= n4) return;
  float4 v = src[i];
  __bf16 o[4] __attribute__((aligned(8))) =
      {(__bf16)v.x, (__bf16)v.y, (__bf16)v.z, (__bf16)v.w};
  *reinterpret_cast<uint2*>(dst + i*4) = *reinterpret_cast<const uint2*>(o);
}

// Split the 5 head weight matrices into bf16 hi/lo Bt form [mat][2][256][KPP].
__global__ void head_wsplit_k(const float* __restrict__ bi, const float* __restrict__ si,
                              const float* __restrict__ cs, const float* __restrict__ fc2,
                              __bf16* __restrict__ W){
  int k = threadIdx.x; if (k >= KPP) return;
  int n = blockIdx.x;            // 0..255
  int mat = blockIdx.y;          // 0..4
  float v = 0.f;
  if (k < D_F){
    if      (mat == 0){ if (n < D_F) v = bi[(long)n*D_F + k]; }
    else if (mat == 1){ if (n < D_F) v = si[(long)n*D_F + k]; }
    else if (mat == 2){ if (n < D_F) v = cs[(long)n*2*D_F + k]; }
    else if (mat == 3){ if (n < D_F) v = cs[(long)n*2*D_F + D_F + k]; }
    else              { if (n < NCL) v = fc2[(long)n*D_F + k]; }
  }
  __bf16 h = (__bf16)v;
  long base = (long)mat*2*BLO + (long)n*KPP + k;
  W[base]       = h;
  W[base + BLO] = (__bf16)(v - (float)h);
}

// ---------------- small fused kernels ----------------

__global__ void conv_bn_relu_k(const int* __restrict__ e1, const int* __restrict__ rel,
                               const __bf16* __restrict__ AEh, const float* __restrict__ embrel,
                               const float* __restrict__ g0, const float* __restrict__ b0,
                               const float* __restrict__ cw, const float* __restrict__ cb,
                               const float* __restrict__ g1, const float* __restrict__ b1,
                               __bf16* __restrict__ out){
  __shared__ float sh[2][D_F];
  int b = blockIdx.y, c0 = blockIdx.x*8, t = threadIdx.x;
  const float inv = rsqrtf(1.0f + 1e-5f);
  if (t < D_F){
    sh[0][t] = (float)AEh[(long)e1[b]*KPP + t] * (g0[0]*inv) + b0[0];
    sh[1][t] = embrel[(long)rel[b]*D_F + t]    * (g0[1]*inv) + b0[1];
  }
  __syncthreads();
  if (t >= D_F) return;
  for (int cc = 0; cc < 8; cc++){
    int c = c0 + cc;
    float sum = cb[c];
    #pragma unroll
    for (int i = 0; i < 2; i++){
      #pragma unroll
      for (int k = 0; k < 5; k++){
        int h = t + k - 2;
        float sv = (h >= 0 && h < D_F) ? sh[i][h] : 0.f;
        sum += sv * cw[(c*2+i)*5 + k];
      }
    }
    float x = sum * (g1[c]*inv) + b1[c];
    out[((long)b*CCH + c)*D_F + t] = (__bf16)fmaxf(x, 0.f);
  }
}

__global__ void fc_fin_k(const float* __restrict__ raw, const float* __restrict__ fb,
                         const float* __restrict__ g, const float* __restrict__ bb,
                         __bf16* __restrict__ x2s){
  int b = blockIdx.x, t = threadIdx.x;
  if (t >= KPP) return;
  float x = 0.f;
  if (t < D_F){
    const float inv = rsqrtf(1.0f + 1e-5f);
    x = (raw[b*D_F + t] + fb[t]) * (g[t]*inv) + bb[t];
    x = fmaxf(x, 0.f);
  }
  __bf16 h = (__bf16)x;
  x2s[(long)b*KPP + t] = h;
  x2s[ALO + (long)b*KPP + t] = (__bf16)(x - (float)h);
}

__global__ void feats_k(const int* __restrict__ attr, const __bf16* __restrict__ AEh,
                        __bf16* __restrict__ hA){
  int b = blockIdx.x, t = threadIdx.x;
  if (t >= KPP) return;
  float s = 0.f, sq = 0.f;
  if (t < D_F){
    #pragma unroll
    for (int a = 0; a < NA_; a++){
      int id = attr[b*NA_ + a];
      float v = (float)AEh[(long)id*KPP + t];
      s += v; sq += v*v;
    }
  }
  float dp = 0.5f*(s*s - sq);
  long o = (long)b*KPP + t;
  __bf16 hd = (__bf16)dp;
  hA[o]            = hd;
  hA[o + ALO]      = (__bf16)(dp - (float)hd);
  __bf16 hs = (__bf16)s;
  hA[o + 2*ALO]    = hs;
  hA[o + 3*ALO]    = (__bf16)(s - (float)hs);
}

// ---------------- launch ----------------

extern "C" void kernel_launch(void* const* d_in, const int* in_sizes, int n_in,
                              void* d_out, int out_size, void* d_ws, size_t ws_size,
                              hipStream_t stream) {
  const int* e1       = (const int*)d_in[0];
  const int* rel      = (const int*)d_in[1];
  const int* attr     = (const int*)d_in[2];
  const int* ei       = (const int*)d_in[4];
  const int* erel     = (const int*)d_in[5];
  const float* emb_e  = (const float*)d_in[6];
  const float* embrel = (const float*)d_in[7];
  const float* alpha1 = (const float*)d_in[8];
  const float* alpha2 = (const float*)d_in[9];
  const float* gc1_W  = (const float*)d_in[10];
  const float* gc1_b  = (const float*)d_in[11];
  const float* gc2_W  = (const float*)d_in[12];
  const float* gc2_b  = (const float*)d_in[13];
  const float* bn3_g  = (const float*)d_in[14];
  const float* bn3_b  = (const float*)d_in[15];
  const float* bn4_g  = (const float*)d_in[16];
  const float* bn4_b  = (const float*)d_in[17];
  const float* bn0_g  = (const float*)d_in[18];
  const float* bn0_b  = (const float*)d_in[19];
  const float* conv_w = (const float*)d_in[20];
  const float* conv_b = (const float*)d_in[21];
  const float* bn1_g  = (const float*)d_in[22];
  const float* bn1_b  = (const float*)d_in[23];
  const float* fc_w   = (const float*)d_in[24];
  const float* fc_b   = (const float*)d_in[25];
  const float* bn2_g  = (const float*)d_in[26];
  const float* bn2_b  = (const float*)d_in[27];
  const float* bi_w   = (const float*)d_in[28];
  const float* bi_b   = (const float*)d_in[29];
  const float* si_w   = (const float*)d_in[30];
  const float* si_b   = (const float*)d_in[31];
  const float* cs_w   = (const float*)d_in[32];
  const float* cs_b   = (const float*)d_in[33];
  const float* fc2_w  = (const float*)d_in[34];
  const float* fc2_b  = (const float*)d_in[35];

  float* pred_out = (float*)d_out;                       // 128 x 100000
  float* clus_out = (float*)d_out + (long)BB*NNODES;     // 128 x 16

  char* w = (char*)d_ws;
  size_t off = 0;
  auto alloc = [&](size_t bytes) -> void* {
    off = (off + 255) & ~(size_t)255;
    void* p = w + off;
    off += bytes;
    return p;
  };
  __bf16* AEh  = (__bf16*)alloc((size_t)MROWS*KPP*2);   // 44.8 MB, final embeddings
  void* bufA   = alloc((size_t)MROWS*KPE*2);            // emb_h (20.8MB) / fcBt (20.5MB)
  void* bufB   = alloc((size_t)MROWS*KP1*2);            // Z1 (25.6MB) / convout (10.3MB)
  __bf16* H1h  = (__bf16*)alloc((size_t)MROWS*KP2*2);   // 32 MB
  __bf16* Z2   = (__bf16*)alloc((size_t)MROWS*KP2*2);   // 32 MB

  int* bcur   = (int*)alloc((size_t)NBUK*4);
  int* start_ = (int*)alloc((size_t)NNODES*4);
  int* deg    = (int*)alloc((size_t)NNODES*4);
  int2* blist = (int2*)alloc((size_t)NBUK*BCAP*8);      // 12.8 MB
  unsigned* adjW = (unsigned*)alloc((size_t)NBUK*BCAP*4); // 6.4 MB
  __bf16* Bt1 = (__bf16*)alloc((size_t)192*KP1*2);
  __bf16* Bt2 = (__bf16*)alloc((size_t)256*KP2*2);
  __bf16* headW = (__bf16*)alloc((size_t)5*2*256*KPP*2);   // 1.15 MB
  __bf16* headA = (__bf16*)alloc((size_t)5*2*128*KPP*2);   // 0.57 MB
  float* x2raw  = (float*)alloc((size_t)BB*D_F*4);

  __bf16* emb_h   = (__bf16*)bufA;   // pitch 104
  __bf16* fcBt    = (__bf16*)bufA;   // 256 x 40000 (emb_h dead after gather1)
  __bf16* Z1      = (__bf16*)bufB;   // pitch 128
  __bf16* convout = (__bf16*)bufB;   // 128 x 40000 (Z1 dead after GEMM1)

  auto HAp = [&](int slot){ return headA + (size_t)slot*2*ALO; };
  auto HWp = [&](int mat){ return headW + (size_t)mat*2*BLO; };

  const int GGB = (NNODES + 3)/4;
  const int MT = MROWS/64;        // 1563
  const int SWZB = 8*((MT + 7)/8);  // 1568, swizzled stripe slots

  // ---- bucketed CSR build ----
  hipMemsetAsync(bcur, 0, (size_t)NBUK*4, stream);
  hipMemsetAsync(x2raw, 0, (size_t)BB*D_F*4, stream);
  bucket_a_k<<<(EDG + 1023)/1024, 256, 0, stream>>>(ei, erel, bcur, blist);
  bucket_b_k<<<NBUK, 256, 0, stream>>>(blist, bcur, adjW, start_, deg);

  // ---- operand prep ----
  emb_to_bf16_k<<<(NNODES + 7)/8, 256, 0, stream>>>(emb_e, emb_h);
  transpose_w_k<<<192, 128, 0, stream>>>(gc1_W, Bt1, INIT_F, GC1_F, KP1);
  transpose_w_k<<<256, 128, 0, stream>>>(gc2_W, Bt2, GC1_F, D_F, KP2);
  head_wsplit_k<<<dim3(256,5), 256, 0, stream>>>(bi_w, si_w, cs_w, fc2_w, headW);

  // ---- GCN layer 1 ----
  gather_g<4,13,KPE,KP1><<<GGB, 256, 0, stream>>>(emb_h, start_, deg, adjW, alpha1, Z1);
  mfma_gcn<KP1,KP2,3><<<SWZB*3, 256, 0, stream>>>(Z1, Bt1, H1h,
                                                  gc1_b, bn3_g, bn3_b, NNODES, GC1_F);

  // ---- GCN layer 2 ----
  gather_g<3,20,KP2,KP2><<<GGB, 256, 0, stream>>>(H1h, start_, deg, adjW, alpha2, Z2);
  mfma_gcn<KP2,KPP,4><<<SWZB*4, 256, 0, stream>>>(Z2, Bt2, AEh,
                                                  gc2_b, bn4_g, bn4_b, NNODES, D_F);

  // ---- conv head (convout emitted as bf16 fc A-operand) ----
  {
    dim3 grid(CCH/8, BB);
    conv_bn_relu_k<<<grid, 256, 0, stream>>>(e1, rel, AEh, embrel, bn0_g, bn0_b,
                                             conv_w, conv_b, bn1_g, bn1_b, convout);
  }
  {
    long n4 = (long)D_F*FCK/4;   // 2,000,000
    f32_to_bf16_flat_k<<<(int)((n4 + 255)/256), 256, 0, stream>>>(
        (const float4*)fc_w, fcBt, n4);
  }
  {
    dim3 grid(2, 2, 125);
    mfma_fc_k<<<grid, 256, 0, stream>>>(convout, fcBt, x2raw, BB, D_F, 320);
  }
  fc_fin_k<<<BB, 256, 0, stream>>>(x2raw, fc_b, bn2_g, bn2_b, HAp(2));

  // ---- NFM branch (direct-load hi/lo MFMA) ----
  feats_k<<<BB, 256, 0, stream>>>(attr, AEh, headA);
  {
    dim3 grid(4, 2);
    // nfm(slot3) = lrelu(deep@bi^T + bi_b) + lrelu(ssum@si^T + si_b)
    mfma_head_k<2,0,true><<<grid, 256, 0, stream>>>(
        HAp(0), HWp(0), HAp(1), HWp(1), bi_b, si_b, nullptr, HAp(3), 0, D_F);
    // userb(slot4) = lrelu(nfm@cs1^T + x2@cs2^T + cs_b)
    mfma_head_k<2,1,true><<<grid, 256, 0, stream>>>(
        HAp(3), HWp(2), HAp(2), HWp(3), cs_b, nullptr, nullptr, HAp(4), 0, D_F);
  }

  // ---- outputs ----
  {
    // pred = sigmoid(userb_hi @ AEh^T) : M=128, N=100000; AEh read once
    dim3 grid(MT, 1);
    mfma_gemm<KPP,2,8><<<grid, 512, 0, stream>>>(HAp(4), AEh, pred_out, NNODES, BB, NNODES);
  }
  {
    // clusters = sigmoid(userb @ fc2_w^T + fc2_b) : M=128, N=16 (hi/lo MFMA)
    dim3 grid(1, 2);
    mfma_head_k<1,2,false><<<grid, 256, 0, stream>>>(
        HAp(4), HWp(4), nullptr, nullptr, fc2_b, nullptr, clus_out, nullptr, NCL, NCL);
  }
}

// Round 9
// 609.825 us; speedup vs baseline: 1.0105x; 1.0105x over previous
//
#include <hip/hip_runtime.h>
#include <hip/hip_bf16.h>
#include <math.h>

// Problem constants (from reference setup_inputs)
#define NNODES 100000
#define INIT_F 100
#define GC1_F  150
#define D_F    200
#define CCH    200
#define BB     128
#define NA_    8
#define EDG    500000
#define NCL    16

#define MROWS  100032   // 1563 * 64, padded row count
#define MT_    (MROWS/64)   // 1563 row stripes

// bf16 K-padded pitches (elements)
#define KPE    104      // emb_h pitch: 100 -> 104 (13 lanes * 8)
#define KP1    128      // layer1 GEMM K: 100 -> 128
#define KP2    160      // layer2 input features: 150 -> 160
#define KPP    224      // head features: 200 -> 224
#define FCK    40000    // fc K

// bucketed CSR build
#define NPB    256                       // nodes per bucket
#define NBUK   ((NNODES + NPB - 1)/NPB)  // 391
#define BCAP   4096                      // slots per bucket

// head hi/lo layout strides (elements)
#define ALO ((long)128*KPP)      // A-side: [slot][2][128][KPP]; lo = hi + ALO
#define BLO ((long)256*KPP)      // B-side: [mat][2][256][KPP];  lo = hi + BLO

typedef __attribute__((ext_vector_type(8))) __bf16 bf16x8;
typedef __attribute__((ext_vector_type(4))) float  f32x4;

__device__ __forceinline__ float fast_tanh(float z){
  // tanh(z) = 1 - 2/(exp(2z)+1); v_exp + v_rcp, ~1e-6 rel.
  float ex = __expf(2.f*z);
  return 1.f - 2.f/(ex + 1.f);
}

// ---------------- bucketed CSR build ----------------

__global__ __launch_bounds__(256) void bucket_a_k(
    const int* __restrict__ ei, const int* __restrict__ erel,
    int* __restrict__ bcur, int2* __restrict__ blist)
{
  __shared__ int hist[NBUK];
  int t = threadIdx.x;
  for (int i = t; i < NBUK; i += 256) hist[i] = 0;
  __syncthreads();
  int e0 = blockIdx.x*1024;
  int rr[4], cc[4], pl[4], rkA[4], rkB[4];
  #pragma unroll
  for (int i = 0; i < 4; i++){
    int e = e0 + i*256 + t;
    bool ok = e < EDG;
    rr[i] = ok ? ei[e]       : -1;
    cc[i] = ok ? ei[EDG + e] : 0;
    pl[i] = (ok ? erel[e] : 0) << 17;
    if (ok){
      rkA[i] = atomicAdd(&hist[rr[i] >> 8], 1);
      rkB[i] = atomicAdd(&hist[cc[i] >> 8], 1);
    }
  }
  __syncthreads();
  for (int i = t; i < NBUK; i += 256){
    int c = hist[i];
    hist[i] = c ? atomicAdd(&bcur[i], c) : 0;
  }
  __syncthreads();
  #pragma unroll
  for (int i = 0; i < 4; i++){
    if (rr[i] < 0) continue;
    int bA = rr[i] >> 8, bB = cc[i] >> 8;
    int sA = hist[bA] + rkA[i];
    int sB = hist[bB] + rkB[i];
    if (sA < BCAP) blist[(long)bA*BCAP + sA] = make_int2(rr[i], cc[i] | pl[i]);
    if (sB < BCAP) blist[(long)bB*BCAP + sB] = make_int2(cc[i], rr[i] | pl[i]);
  }
}

__global__ __launch_bounds__(256) void bucket_b_k(
    const int2* __restrict__ blist, const int* __restrict__ bcur,
    unsigned* __restrict__ adjW, int* __restrict__ start_, int* __restrict__ deg_)
{
  __shared__ int cnt[NPB];
  __shared__ int sc[NPB];
  int b = blockIdx.x, t = threadIdx.x;
  cnt[t] = 0;
  __syncthreads();
  int n = min(bcur[b], BCAP);
  const int2* bl = blist + (long)b*BCAP;
  for (int i = t; i < n; i += 256) atomicAdd(&cnt[bl[i].x & (NPB-1)], 1);
  __syncthreads();
  int v = cnt[t]; sc[t] = v; __syncthreads();
  for (int off = 1; off < NPB; off <<= 1){
    int x = (t >= off) ? sc[t-off] : 0;
    __syncthreads();
    sc[t] += x; __syncthreads();
  }
  int excl = sc[t] - v;
  int node = b*NPB + t;
  if (node < NNODES){ start_[node] = b*BCAP + excl; deg_[node] = v; }
  cnt[t] = excl;
  __syncthreads();
  for (int i = t; i < n; i += 256){
    int2 rec = bl[i];
    int s = atomicAdd(&cnt[rec.x & (NPB-1)], 1);
    adjW[(long)b*BCAP + s] = (unsigned)rec.y;
  }
}

// ---------------- fused GCN layer: gather -> LDS -> MFMA GEMM -> bn+tanh ----
// One 1024-thread block (16 waves) per 64-row stripe.
// Phase 1: each wave gathers 4 nodes (G lane-groups of LPG lanes, 4 rows in
// flight per group) into a padded LDS tile As[64][KP+8] (+8 elems -> <=2-way
// bank aliasing on the stride-KP phase-2 reads).
// Phase 2: 16 waves as 4x4 (row x col-64) compute the 64xPHO GEMM with A
// from LDS and B (zero-padded to 256 rows) from L2, fused bias+bn+tanh.
// This deletes the Z round-trip through HBM and the separate latency-bound
// GEMM dispatch (pinned at ~62us across rounds 4/6/8 regardless of traffic).
// adjW entry: u | (rel << 17).

template<int G, int LPG, int PIN, int KP, int PHO>
__global__ __launch_bounds__(1024) void gcn_layer_k(
    const __bf16* __restrict__ X, const int* __restrict__ start,
    const int* __restrict__ degv, const unsigned* __restrict__ adjW,
    const float* __restrict__ alpha,
    const __bf16* __restrict__ Bt, __bf16* __restrict__ C,
    const float* __restrict__ gb, const float* __restrict__ bng,
    const float* __restrict__ bnb, int M, int N)
{
  constexpr int KPAD = KP + 8;
  __shared__ __bf16 As[64][KPAD];
  int w = threadIdx.x >> 6;          // wave 0..15
  int lane = threadIdx.x & 63;
  int vbase = blockIdx.x*64;
  int grp = lane / LPG;
  int li  = lane - grp*LPG;
  bool act = grp < G;

  // ---- phase 1: gather 4 nodes per wave into LDS rows w*4+q4 ----
  for (int q4 = 0; q4 < 4; q4++){
    int row = w*4 + q4;
    int v = vbase + row;               // wave-uniform
    float acc[8] = {};
    if (v < NNODES){
      int s = start[v], e = s + degv[v];
      for (int jb = s; jb < e; jb += 4*G){
        int u[4]; float wt[4];
        #pragma unroll
        for (int q = 0; q < 4; q++){
          int j = jb + grp + q*G;
          u[q] = 0; wt[q] = 0.f;
          if (act && j < e){ unsigned pr = adjW[j]; u[q] = pr & 0x1FFFF; wt[q] = alpha[pr >> 17]; }
        }
        bf16x8 rows[4];
        #pragma unroll
        for (int q = 0; q < 4; q++)
          rows[q] = *(const bf16x8*)(X + (long)u[q]*PIN + li*8);
        #pragma unroll
        for (int q = 0; q < 4; q++)
          #pragma unroll
          for (int i = 0; i < 8; i++)
            acc[i] += wt[q]*(float)rows[q][i];
      }
      #pragma unroll
      for (int g = 1; g < G; g++)
        #pragma unroll
        for (int i = 0; i < 8; i++)
          acc[i] += __shfl(acc[i], lane + g*LPG, 64);
    }
    if (lane < LPG){
      bf16x8 o;
      #pragma unroll
      for (int i = 0; i < 8; i++) o[i] = (__bf16)acc[i];
      *(bf16x8*)(&As[row][lane*8]) = o;
    } else if (lane < KP/8){
      bf16x8 o = {};
      *(bf16x8*)(&As[row][lane*8]) = o;
    }
  }
  __syncthreads();

  // ---- phase 2: 64 x PHO GEMM from LDS; waves = 4 rows x 4 col-tiles ----
  int wrow = w & 3, wcol = w >> 2;
  int n0 = wcol*64;
  if (n0 >= PHO) return;
  int ml = lane & 15, kq = lane >> 4;
  int m0 = wrow*16;
  const __bf16* Bp = Bt + (long)(n0 + ml)*KP + kq*8;
  f32x4 acc2[4] = {};
  #pragma unroll
  for (int k0 = 0; k0 < KP; k0 += 32){
    bf16x8 a = *(const bf16x8*)(&As[m0 + ml][kq*8 + k0]);
    #pragma unroll
    for (int t = 0; t < 4; t++){
      bf16x8 b = *(const bf16x8*)(Bp + (long)t*16*KP + k0);
      acc2[t] = __builtin_amdgcn_mfma_f32_16x16x32_bf16(a, b, acc2[t], 0, 0, 0);
    }
  }
  const float inv = rsqrtf(1.0f + 1e-5f);
  int mr = vbase + m0 + kq*4;
  #pragma unroll
  for (int t = 0; t < 4; t++){
    int gn = n0 + t*16 + ml;
    if (gn >= PHO) continue;
    bool real = gn < N;
    float gbb = real ? gb[gn] : 0.f;
    float sc  = real ? bng[gn]*inv : 0.f;
    float bb_ = real ? bnb[gn] : 0.f;
    #pragma unroll
    for (int r = 0; r < 4; r++){
      int gm = mr + r;
      if (gm < M){
        float xg = real ? fast_tanh((acc2[t][r] + gbb)*sc + bb_) : 0.f;
        C[(long)gm*PHO + gn] = (__bf16)xg;
      }
    }
  }
}

// ---------------- bf16 MFMA GEMM, fp32 out (pred) ----------------

template<int KP, int ACT, int WPB>
__global__ __launch_bounds__(WPB*64) void mfma_gemm(
    const __bf16* __restrict__ A, const __bf16* __restrict__ Bt,
    float* __restrict__ C, long ldc, int M, int N)
{
  int w = threadIdx.x >> 6, l = threadIdx.x & 63;
  int m0 = blockIdx.y*(WPB*16) + w*16;
  int n0 = blockIdx.x*64;
  int ml = l & 15, kq = l >> 4;
  const __bf16* Ap = A  + (long)(m0 + ml)*KP + kq*8;
  const __bf16* Bp = Bt + (long)(n0 + ml)*KP + kq*8;
  f32x4 acc[4] = {};
  #pragma unroll
  for (int k0 = 0; k0 < KP; k0 += 32){
    bf16x8 a = *(const bf16x8*)(Ap + k0);
    #pragma unroll
    for (int t = 0; t < 4; t++){
      bf16x8 b = *(const bf16x8*)(Bp + (long)t*16*KP + k0);
      acc[t] = __builtin_amdgcn_mfma_f32_16x16x32_bf16(a, b, acc[t], 0, 0, 0);
    }
  }
  int mr = m0 + kq*4;
  #pragma unroll
  for (int t = 0; t < 4; t++){
    int gn = n0 + t*16 + ml;
    if (gn >= N) continue;
    #pragma unroll
    for (int r = 0; r < 4; r++){
      int gm = mr + r;
      if (gm < M){
        float x = acc[t][r];
        if (ACT == 2) x = 1.f/(1.f + __expf(-x));
        C[(long)gm*ldc + gn] = x;
      }
    }
  }
}

// ---------------- fc MFMA: split-K, atomic accumulate ----------------

__global__ __launch_bounds__(256) void mfma_fc_k(
    const __bf16* __restrict__ A, const __bf16* __restrict__ Bt,
    float* __restrict__ C, int M, int N, int klen)
{
  int w = threadIdx.x >> 6, l = threadIdx.x & 63;
  int m0 = blockIdx.y*64 + w*16;
  int n0 = blockIdx.x*128;
  long kb = (long)blockIdx.z * klen;
  int ml = l & 15, kq = l >> 4;
  const __bf16* Ap = A  + (long)(m0 + ml)*FCK + kb + kq*8;
  const __bf16* Bp = Bt + (long)(n0 + ml)*FCK + kb + kq*8;
  f32x4 acc[2][4] = {};
  #pragma unroll 2
  for (int k0 = 0; k0 < klen; k0 += 32){
    bf16x8 a = *(const bf16x8*)(Ap + k0);
    #pragma unroll
    for (int c = 0; c < 2; c++)
      #pragma unroll
      for (int t = 0; t < 4; t++){
        bf16x8 b = *(const bf16x8*)(Bp + (long)(c*64 + t*16)*FCK + k0);
        acc[c][t] = __builtin_amdgcn_mfma_f32_16x16x32_bf16(a, b, acc[c][t], 0, 0, 0);
      }
  }
  int mr = m0 + kq*4;
  #pragma unroll
  for (int c = 0; c < 2; c++)
    #pragma unroll
    for (int t = 0; t < 4; t++){
      int gn = n0 + c*64 + t*16 + ml;
      if (gn >= N) continue;
      #pragma unroll
      for (int r = 0; r < 4; r++){
        int gm = mr + r;
        if (gm < M) atomicAdd(&C[(long)gm*N + gn], acc[c][t][r]);
      }
    }
}

// ---------------- head MFMA: direct-load hi/lo bf16 split GEMM ----------------

template<int NPROD, int COMBINE, bool SPLITOUT>
__global__ __launch_bounds__(256) void mfma_head_k(
    const __bf16* __restrict__ A0, const __bf16* __restrict__ B0,
    const __bf16* __restrict__ A1, const __bf16* __restrict__ B1,
    const float* __restrict__ bias0, const float* __restrict__ bias1,
    float* __restrict__ outF, __bf16* __restrict__ outS,
    int ldc, int N)
{
  int w = threadIdx.x >> 6, l = threadIdx.x & 63;
  int m0 = blockIdx.y*64 + w*16;
  int n0 = blockIdx.x*64;
  int ml = l & 15, kq = l >> 4;
  long aoff = (long)(m0 + ml)*KPP + kq*8;
  long boff = (long)(n0 + ml)*KPP + kq*8;
  f32x4 accA[4] = {}, accB[4] = {};
  #pragma unroll
  for (int k0 = 0; k0 < KPP; k0 += 32){
    bf16x8 ah = *(const bf16x8*)(A0 + aoff + k0);
    bf16x8 al = *(const bf16x8*)(A0 + ALO + aoff + k0);
    #pragma unroll
    for (int t = 0; t < 4; t++){
      bf16x8 bh = *(const bf16x8*)(B0 + boff + (long)t*16*KPP + k0);
      bf16x8 bl = *(const bf16x8*)(B0 + BLO + boff + (long)t*16*KPP + k0);
      accA[t] = __builtin_amdgcn_mfma_f32_16x16x32_bf16(ah, bh, accA[t], 0, 0, 0);
      accA[t] = __builtin_amdgcn_mfma_f32_16x16x32_bf16(al, bh, accA[t], 0, 0, 0);
      accA[t] = __builtin_amdgcn_mfma_f32_16x16x32_bf16(ah, bl, accA[t], 0, 0, 0);
    }
    if constexpr (NPROD == 2){
      bf16x8 ch = *(const bf16x8*)(A1 + aoff + k0);
      bf16x8 cl = *(const bf16x8*)(A1 + ALO + aoff + k0);
      #pragma unroll
      for (int t = 0; t < 4; t++){
        bf16x8 bh = *(const bf16x8*)(B1 + boff + (long)t*16*KPP + k0);
        bf16x8 bl = *(const bf16x8*)(B1 + BLO + boff + (long)t*16*KPP + k0);
        accB[t] = __builtin_amdgcn_mfma_f32_16x16x32_bf16(ch, bh, accB[t], 0, 0, 0);
        accB[t] = __builtin_amdgcn_mfma_f32_16x16x32_bf16(cl, bh, accB[t], 0, 0, 0);
        accB[t] = __builtin_amdgcn_mfma_f32_16x16x32_bf16(ch, bl, accB[t], 0, 0, 0);
      }
    }
  }
  int mr = m0 + kq*4;
  #pragma unroll
  for (int t = 0; t < 4; t++){
    int gn = n0 + t*16 + ml;
    if (SPLITOUT){ if (gn >= KPP) continue; }
    else         { if (gn >= N)   continue; }
    bool real = gn < N;
    float bb0 = real ? bias0[gn] : 0.f;
    float bb1 = (COMBINE == 0 && real) ? bias1[gn] : 0.f;
    #pragma unroll
    for (int r = 0; r < 4; r++){
      int gm = mr + r;
      float x;
      if (COMBINE == 0){
        float xa = accA[t][r] + bb0; xa = (xa >= 0.f) ? xa : 0.01f*xa;
        float xb = accB[t][r] + bb1; xb = (xb >= 0.f) ? xb : 0.01f*xb;
        x = xa + xb;
      } else if (COMBINE == 1){
        x = accA[t][r] + accB[t][r] + bb0;
        x = (x >= 0.f) ? x : 0.01f*x;
      } else {
        x = accA[t][r] + bb0;
        x = 1.f/(1.f + __expf(-x));
      }
      if (!real) x = 0.f;
      if (SPLITOUT){
        __bf16 h = (__bf16)x;
        outS[(long)gm*KPP + gn] = h;
        outS[ALO + (long)gm*KPP + gn] = (__bf16)(x - (float)h);
      } else {
        outF[(long)gm*ldc + gn] = x;
      }
    }
  }
}

// ---------------- conversion helpers ----------------

__global__ __launch_bounds__(256) void emb_to_bf16_k(const float* __restrict__ src,
                                                     __bf16* __restrict__ dst){
  int lane = threadIdx.x & 63;
  int half = lane >> 5, l = lane & 31;
  long r = (long)blockIdx.x*8 + (threadIdx.x >> 6)*2 + half;
  if (r >= NNODES || l >= 26) return;
  float4 v = make_float4(0.f, 0.f, 0.f, 0.f);
  if (l < 25) v = *(const float4*)(src + r*INIT_F + l*4);
  __bf16 o[4] __attribute__((aligned(8))) =
      {(__bf16)v.x, (__bf16)v.y, (__bf16)v.z, (__bf16)v.w};
  *reinterpret_cast<uint2*>(dst + r*KPE + l*4) = *reinterpret_cast<const uint2*>(o);
}

__global__ void transpose_w_k(const float* __restrict__ W, __bf16* __restrict__ Bt,
                              int K, int N, int Kp){
  int n = blockIdx.x;
  for (int k = threadIdx.x; k < Kp; k += blockDim.x){
    float v = (k < K && n < N) ? W[(long)k*N + n] : 0.f;
    Bt[(long)n*Kp + k] = (__bf16)v;
  }
}

__global__ void f32_to_bf16_flat_k(const float4* __restrict__ src,
                                   __bf16* __restrict__ dst, long n4){
  long i = (long)blockIdx.x*256 + threadIdx.x;
  if (i >= n4) return;
  float4 v = src[i];
  __bf16 o[4] __attribute__((aligned(8))) =
      {(__bf16)v.x, (__bf16)v.y, (__bf16)v.z, (__bf16)v.w};
  *reinterpret_cast<uint2*>(dst + i*4) = *reinterpret_cast<const uint2*>(o);
}

// Split the 5 head weight matrices into bf16 hi/lo Bt form [mat][2][256][KPP].
__global__ void head_wsplit_k(const float* __restrict__ bi, const float* __restrict__ si,
                              const float* __restrict__ cs, const float* __restrict__ fc2,
                              __bf16* __restrict__ W){
  int k = threadIdx.x; if (k >= KPP) return;
  int n = blockIdx.x;            // 0..255
  int mat = blockIdx.y;          // 0..4
  float v = 0.f;
  if (k < D_F){
    if      (mat == 0){ if (n < D_F) v = bi[(long)n*D_F + k]; }
    else if (mat == 1){ if (n < D_F) v = si[(long)n*D_F + k]; }
    else if (mat == 2){ if (n < D_F) v = cs[(long)n*2*D_F + k]; }
    else if (mat == 3){ if (n < D_F) v = cs[(long)n*2*D_F + D_F + k]; }
    else              { if (n < NCL) v = fc2[(long)n*D_F + k]; }
  }
  __bf16 h = (__bf16)v;
  long base = (long)mat*2*BLO + (long)n*KPP + k;
  W[base]       = h;
  W[base + BLO] = (__bf16)(v - (float)h);
}

// ---------------- small fused kernels ----------------

__global__ void conv_bn_relu_k(const int* __restrict__ e1, const int* __restrict__ rel,
                               const __bf16* __restrict__ AEh, const float* __restrict__ embrel,
                               const float* __restrict__ g0, const float* __restrict__ b0,
                               const float* __restrict__ cw, const float* __restrict__ cb,
                               const float* __restrict__ g1, const float* __restrict__ b1,
                               __bf16* __restrict__ out){
  __shared__ float sh[2][D_F];
  int b = blockIdx.y, c0 = blockIdx.x*8, t = threadIdx.x;
  const float inv = rsqrtf(1.0f + 1e-5f);
  if (t < D_F){
    sh[0][t] = (float)AEh[(long)e1[b]*KPP + t] * (g0[0]*inv) + b0[0];
    sh[1][t] = embrel[(long)rel[b]*D_F + t]    * (g0[1]*inv) + b0[1];
  }
  __syncthreads();
  if (t >= D_F) return;
  for (int cc = 0; cc < 8; cc++){
    int c = c0 + cc;
    float sum = cb[c];
    #pragma unroll
    for (int i = 0; i < 2; i++){
      #pragma unroll
      for (int k = 0; k < 5; k++){
        int h = t + k - 2;
        float sv = (h >= 0 && h < D_F) ? sh[i][h] : 0.f;
        sum += sv * cw[(c*2+i)*5 + k];
      }
    }
    float x = sum * (g1[c]*inv) + b1[c];
    out[((long)b*CCH + c)*D_F + t] = (__bf16)fmaxf(x, 0.f);
  }
}

__global__ void fc_fin_k(const float* __restrict__ raw, const float* __restrict__ fb,
                         const float* __restrict__ g, const float* __restrict__ bb,
                         __bf16* __restrict__ x2s){
  int b = blockIdx.x, t = threadIdx.x;
  if (t >= KPP) return;
  float x = 0.f;
  if (t < D_F){
    const float inv = rsqrtf(1.0f + 1e-5f);
    x = (raw[b*D_F + t] + fb[t]) * (g[t]*inv) + bb[t];
    x = fmaxf(x, 0.f);
  }
  __bf16 h = (__bf16)x;
  x2s[(long)b*KPP + t] = h;
  x2s[ALO + (long)b*KPP + t] = (__bf16)(x - (float)h);
}

__global__ void feats_k(const int* __restrict__ attr, const __bf16* __restrict__ AEh,
                        __bf16* __restrict__ hA){
  int b = blockIdx.x, t = threadIdx.x;
  if (t >= KPP) return;
  float s = 0.f, sq = 0.f;
  if (t < D_F){
    #pragma unroll
    for (int a = 0; a < NA_; a++){
      int id = attr[b*NA_ + a];
      float v = (float)AEh[(long)id*KPP + t];
      s += v; sq += v*v;
    }
  }
  float dp = 0.5f*(s*s - sq);
  long o = (long)b*KPP + t;
  __bf16 hd = (__bf16)dp;
  hA[o]            = hd;
  hA[o + ALO]      = (__bf16)(dp - (float)hd);
  __bf16 hs = (__bf16)s;
  hA[o + 2*ALO]    = hs;
  hA[o + 3*ALO]    = (__bf16)(s - (float)hs);
}

// ---------------- launch ----------------

extern "C" void kernel_launch(void* const* d_in, const int* in_sizes, int n_in,
                              void* d_out, int out_size, void* d_ws, size_t ws_size,
                              hipStream_t stream) {
  const int* e1       = (const int*)d_in[0];
  const int* rel      = (const int*)d_in[1];
  const int* attr     = (const int*)d_in[2];
  const int* ei       = (const int*)d_in[4];
  const int* erel     = (const int*)d_in[5];
  const float* emb_e  = (const float*)d_in[6];
  const float* embrel = (const float*)d_in[7];
  const float* alpha1 = (const float*)d_in[8];
  const float* alpha2 = (const float*)d_in[9];
  const float* gc1_W  = (const float*)d_in[10];
  const float* gc1_b  = (const float*)d_in[11];
  const float* gc2_W  = (const float*)d_in[12];
  const float* gc2_b  = (const float*)d_in[13];
  const float* bn3_g  = (const float*)d_in[14];
  const float* bn3_b  = (const float*)d_in[15];
  const float* bn4_g  = (const float*)d_in[16];
  const float* bn4_b  = (const float*)d_in[17];
  const float* bn0_g  = (const float*)d_in[18];
  const float* bn0_b  = (const float*)d_in[19];
  const float* conv_w = (const float*)d_in[20];
  const float* conv_b = (const float*)d_in[21];
  const float* bn1_g  = (const float*)d_in[22];
  const float* bn1_b  = (const float*)d_in[23];
  const float* fc_w   = (const float*)d_in[24];
  const float* fc_b   = (const float*)d_in[25];
  const float* bn2_g  = (const float*)d_in[26];
  const float* bn2_b  = (const float*)d_in[27];
  const float* bi_w   = (const float*)d_in[28];
  const float* bi_b   = (const float*)d_in[29];
  const float* si_w   = (const float*)d_in[30];
  const float* si_b   = (const float*)d_in[31];
  const float* cs_w   = (const float*)d_in[32];
  const float* cs_b   = (const float*)d_in[33];
  const float* fc2_w  = (const float*)d_in[34];
  const float* fc2_b  = (const float*)d_in[35];

  float* pred_out = (float*)d_out;                       // 128 x 100000
  float* clus_out = (float*)d_out + (long)BB*NNODES;     // 128 x 16

  char* w = (char*)d_ws;
  size_t off = 0;
  auto alloc = [&](size_t bytes) -> void* {
    off = (off + 255) & ~(size_t)255;
    void* p = w + off;
    off += bytes;
    return p;
  };
  __bf16* AEh  = (__bf16*)alloc((size_t)MROWS*KPP*2);   // 44.8 MB, final embeddings
  void* bufA   = alloc((size_t)MROWS*KPE*2);            // emb_h (20.8MB) / fcBt (20.5MB)
  void* bufB   = alloc((size_t)BB*FCK*2);               // convout (10.3MB)
  __bf16* H1h  = (__bf16*)alloc((size_t)MROWS*KP2*2);   // 32 MB

  int* bcur   = (int*)alloc((size_t)NBUK*4);
  int* start_ = (int*)alloc((size_t)NNODES*4);
  int* deg    = (int*)alloc((size_t)NNODES*4);
  int2* blist = (int2*)alloc((size_t)NBUK*BCAP*8);      // 12.8 MB
  unsigned* adjW = (unsigned*)alloc((size_t)NBUK*BCAP*4); // 6.4 MB
  __bf16* Bt1 = (__bf16*)alloc((size_t)256*KP1*2);      // 256 rows, zero-padded
  __bf16* Bt2 = (__bf16*)alloc((size_t)256*KP2*2);
  __bf16* headW = (__bf16*)alloc((size_t)5*2*256*KPP*2);   // 1.15 MB
  __bf16* headA = (__bf16*)alloc((size_t)5*2*128*KPP*2);   // 0.57 MB
  float* x2raw  = (float*)alloc((size_t)BB*D_F*4);

  __bf16* emb_h   = (__bf16*)bufA;   // pitch 104
  __bf16* fcBt    = (__bf16*)bufA;   // 256 x 40000 (emb_h dead after layer 1)
  __bf16* convout = (__bf16*)bufB;   // 128 x 40000

  auto HAp = [&](int slot){ return headA + (size_t)slot*2*ALO; };
  auto HWp = [&](int mat){ return headW + (size_t)mat*2*BLO; };

  const int MT = MROWS/64;        // 1563

  // ---- bucketed CSR build ----
  hipMemsetAsync(bcur, 0, (size_t)NBUK*4, stream);
  hipMemsetAsync(x2raw, 0, (size_t)BB*D_F*4, stream);
  bucket_a_k<<<(EDG + 1023)/1024, 256, 0, stream>>>(ei, erel, bcur, blist);
  bucket_b_k<<<NBUK, 256, 0, stream>>>(blist, bcur, adjW, start_, deg);

  // ---- operand prep ----
  emb_to_bf16_k<<<(NNODES + 7)/8, 256, 0, stream>>>(emb_e, emb_h);
  transpose_w_k<<<256, 128, 0, stream>>>(gc1_W, Bt1, INIT_F, GC1_F, KP1);
  transpose_w_k<<<256, 128, 0, stream>>>(gc2_W, Bt2, GC1_F, D_F, KP2);
  head_wsplit_k<<<dim3(256,5), 256, 0, stream>>>(bi_w, si_w, cs_w, fc2_w, headW);

  // ---- GCN layer 1 (fused gather + GEMM): H1h = tanh(bn3(agg(emb_h)@W1 + b1)) ----
  gcn_layer_k<4,13,KPE,KP1,KP2><<<MT, 1024, 0, stream>>>(
      emb_h, start_, deg, adjW, alpha1, Bt1, H1h, gc1_b, bn3_g, bn3_b, NNODES, GC1_F);

  // ---- GCN layer 2 (fused): AEh = tanh(bn4(agg(H1h)@W2 + b2)) ----
  gcn_layer_k<3,20,KP2,KP2,KPP><<<MT, 1024, 0, stream>>>(
      H1h, start_, deg, adjW, alpha2, Bt2, AEh, gc2_b, bn4_g, bn4_b, NNODES, D_F);

  // ---- conv head (convout emitted as bf16 fc A-operand) ----
  {
    dim3 grid(CCH/8, BB);
    conv_bn_relu_k<<<grid, 256, 0, stream>>>(e1, rel, AEh, embrel, bn0_g, bn0_b,
                                             conv_w, conv_b, bn1_g, bn1_b, convout);
  }
  {
    long n4 = (long)D_F*FCK/4;   // 2,000,000
    f32_to_bf16_flat_k<<<(int)((n4 + 255)/256), 256, 0, stream>>>(
        (const float4*)fc_w, fcBt, n4);
  }
  {
    dim3 grid(2, 2, 125);
    mfma_fc_k<<<grid, 256, 0, stream>>>(convout, fcBt, x2raw, BB, D_F, 320);
  }
  fc_fin_k<<<BB, 256, 0, stream>>>(x2raw, fc_b, bn2_g, bn2_b, HAp(2));

  // ---- NFM branch (direct-load hi/lo MFMA) ----
  feats_k<<<BB, 256, 0, stream>>>(attr, AEh, headA);
  {
    dim3 grid(4, 2);
    // nfm(slot3) = lrelu(deep@bi^T + bi_b) + lrelu(ssum@si^T + si_b)
    mfma_head_k<2,0,true><<<grid, 256, 0, stream>>>(
        HAp(0), HWp(0), HAp(1), HWp(1), bi_b, si_b, nullptr, HAp(3), 0, D_F);
    // userb(slot4) = lrelu(nfm@cs1^T + x2@cs2^T + cs_b)
    mfma_head_k<2,1,true><<<grid, 256, 0, stream>>>(
        HAp(3), HWp(2), HAp(2), HWp(3), cs_b, nullptr, nullptr, HAp(4), 0, D_F);
  }

  // ---- outputs ----
  {
    // pred = sigmoid(userb_hi @ AEh^T) : M=128, N=100000; AEh read once
    dim3 grid(MT, 1);
    mfma_gemm<KPP,2,8><<<grid, 512, 0, stream>>>(HAp(4), AEh, pred_out, NNODES, BB, NNODES);
  }
  {
    // clusters = sigmoid(userb @ fc2_w^T + fc2_b) : M=128, N=16 (hi/lo MFMA)
    dim3 grid(1, 2);
    mfma_head_k<1,2,false><<<grid, 256, 0, stream>>>(
        HAp(4), HWp(4), nullptr, nullptr, fc2_b, nullptr, clus_out, nullptr, NCL, NCL);
  }
}

// Round 10
// 578.355 us; speedup vs baseline: 1.0655x; 1.0544x over previous
//
#include <hip/hip_runtime.h>
#include <hip/hip_bf16.h>
#include <math.h>

// Problem constants (from reference setup_inputs)
#define NNODES 100000
#define INIT_F 100
#define GC1_F  150
#define D_F    200
#define CCH    200
#define BB     128
#define NA_    8
#define EDG    500000
#define NCL    16

#define MROWS  100032   // 1563 * 64, padded row count (pred B operand)
#define MT_    (MROWS/64)

// bf16 K-padded pitches (elements)
#define KPE    104      // emb_h pitch: 100 -> 104 (13 lanes * 8)
#define KP1    128      // layer1 GEMM K: 100 -> 128
#define KP2    160      // layer2 input features: 150 -> 160
#define KPP    224      // head features: 200 -> 224
#define FCK    40000    // fc K

// bucketed CSR build
#define NPB    256                       // nodes per bucket
#define NBUK   ((NNODES + NPB - 1)/NPB)  // 391
#define BCAP   4096                      // slots per bucket

// head hi/lo layout strides (elements)
#define ALO ((long)128*KPP)      // A-side: [slot][2][128][KPP]; lo = hi + ALO
#define BLO ((long)256*KPP)      // B-side: [mat][2][256][KPP];  lo = hi + BLO

typedef __attribute__((ext_vector_type(8))) __bf16 bf16x8;
typedef __attribute__((ext_vector_type(4))) float  f32x4;

__device__ __forceinline__ float fast_tanh(float z){
  float ex = __expf(2.f*z);
  return 1.f - 2.f/(ex + 1.f);
}

// ---------------- bucketed CSR build ----------------

__global__ __launch_bounds__(256) void bucket_a_k(
    const int* __restrict__ ei, const int* __restrict__ erel,
    int* __restrict__ bcur, int2* __restrict__ blist)
{
  __shared__ int hist[NBUK];
  int t = threadIdx.x;
  for (int i = t; i < NBUK; i += 256) hist[i] = 0;
  __syncthreads();
  int e0 = blockIdx.x*1024;
  int rr[4], cc[4], pl[4], rkA[4], rkB[4];
  #pragma unroll
  for (int i = 0; i < 4; i++){
    int e = e0 + i*256 + t;
    bool ok = e < EDG;
    rr[i] = ok ? ei[e]       : -1;
    cc[i] = ok ? ei[EDG + e] : 0;
    pl[i] = (ok ? erel[e] : 0) << 17;
    if (ok){
      rkA[i] = atomicAdd(&hist[rr[i] >> 8], 1);
      rkB[i] = atomicAdd(&hist[cc[i] >> 8], 1);
    }
  }
  __syncthreads();
  for (int i = t; i < NBUK; i += 256){
    int c = hist[i];
    hist[i] = c ? atomicAdd(&bcur[i], c) : 0;
  }
  __syncthreads();
  #pragma unroll
  for (int i = 0; i < 4; i++){
    if (rr[i] < 0) continue;
    int bA = rr[i] >> 8, bB = cc[i] >> 8;
    int sA = hist[bA] + rkA[i];
    int sB = hist[bB] + rkB[i];
    if (sA < BCAP) blist[(long)bA*BCAP + sA] = make_int2(rr[i], cc[i] | pl[i]);
    if (sB < BCAP) blist[(long)bB*BCAP + sB] = make_int2(cc[i], rr[i] | pl[i]);
  }
}

__global__ __launch_bounds__(256) void bucket_b_k(
    const int2* __restrict__ blist, const int* __restrict__ bcur,
    unsigned* __restrict__ adjW, int* __restrict__ start_, int* __restrict__ deg_)
{
  __shared__ int cnt[NPB];
  __shared__ int sc[NPB];
  int b = blockIdx.x, t = threadIdx.x;
  cnt[t] = 0;
  __syncthreads();
  int n = min(bcur[b], BCAP);
  const int2* bl = blist + (long)b*BCAP;
  for (int i = t; i < n; i += 256) atomicAdd(&cnt[bl[i].x & (NPB-1)], 1);
  __syncthreads();
  int v = cnt[t]; sc[t] = v; __syncthreads();
  for (int off = 1; off < NPB; off <<= 1){
    int x = (t >= off) ? sc[t-off] : 0;
    __syncthreads();
    sc[t] += x; __syncthreads();
  }
  int excl = sc[t] - v;
  int node = b*NPB + t;
  if (node < NNODES){ start_[node] = b*BCAP + excl; deg_[node] = v; }
  cnt[t] = excl;
  __syncthreads();
  for (int i = t; i < n; i += 256){
    int2 rec = bl[i];
    int s = atomicAdd(&cnt[rec.x & (NPB-1)], 1);
    adjW[(long)b*BCAP + s] = (unsigned)rec.y;
  }
}

// ---------------- fused GCN layer: gather -> LDS -> MFMA GEMM -> bn+tanh ----
// 512-thread block (8 waves) per 32-row stripe; grid = 100000/32 = 3125.
// Phase 1: wave w gathers nodes v0..v0+3.  int4 start/deg load + cross-node
// adjW prefetch pipeline: node q4+1's first adjW batch is issued BEFORE node
// q4's row loads (independent chains -> genuine overlap the scheduler keeps).
// Phase 2: 8 waves as 2x4 (rowtile x coltile-64) MFMA GEMM from LDS; epilogue
// stages C in LDS and copies out as coalesced bf16x8 rows (replaces 2B/lane
// scattered stores).  adjW entry: u | (rel << 17).

template<int G, int LPG, int PIN, int KP, int PHO>
__global__ __launch_bounds__(512, 6) void gcn_layer_k(
    const __bf16* __restrict__ X, const int* __restrict__ start,
    const int* __restrict__ degv, const unsigned* __restrict__ adjW,
    const float* __restrict__ alpha,
    const __bf16* __restrict__ Bt, __bf16* __restrict__ C,
    const float* __restrict__ gb, const float* __restrict__ bng,
    const float* __restrict__ bnb, int N)
{
  constexpr int KPAD = KP + 8;
  constexpr int LSZ = (KPAD > PHO) ? KPAD : PHO;
  __shared__ __bf16 lds[32 * LSZ];
  int tid = threadIdx.x;
  int w = tid >> 6;
  int lane = tid & 63;
  int vbase = blockIdx.x*32;
  int grp = lane / LPG;
  int li  = lane - grp*LPG;
  bool act = grp < G;

  // ---- phase 1: gather nodes v0..v0+3 into LDS rows w*4..w*4+3 ----
  int v0 = vbase + w*4;
  int4 sv4 = *(const int4*)(start + v0);
  int4 dv4 = *(const int4*)(degv + v0);
  int sA[4] = {sv4.x, sv4.y, sv4.z, sv4.w};
  int eA[4] = {sv4.x + dv4.x, sv4.y + dv4.y, sv4.z + dv4.z, sv4.w + dv4.w};

  unsigned prn[4];
  #pragma unroll
  for (int q = 0; q < 4; q++){
    int j = sA[0] + grp + q*G;
    prn[q] = (act && j < eA[0]) ? adjW[j] : 0u;
  }
  #pragma unroll
  for (int q4 = 0; q4 < 4; q4++){
    int s = sA[q4], e = eA[q4];
    unsigned prc[4] = {prn[0], prn[1], prn[2], prn[3]};
    if (q4 < 3){
      #pragma unroll
      for (int q = 0; q < 4; q++){
        int j = sA[q4+1] + grp + q*G;
        prn[q] = (act && j < eA[q4+1]) ? adjW[j] : 0u;
      }
    }
    float acc[8] = {};
    for (int jb = s; jb < e; jb += 4*G){
      int u[4]; float wt[4];
      #pragma unroll
      for (int q = 0; q < 4; q++){
        int j = jb + grp + q*G;
        u[q]  = prc[q] & 0x1FFFF;
        wt[q] = (act && j < e) ? alpha[prc[q] >> 17] : 0.f;
      }
      if (jb + 4*G < e){
        #pragma unroll
        for (int q = 0; q < 4; q++){
          int j = jb + 4*G + grp + q*G;
          prc[q] = (act && j < e) ? adjW[j] : 0u;
        }
      }
      bf16x8 rows[4];
      #pragma unroll
      for (int q = 0; q < 4; q++)
        rows[q] = *(const bf16x8*)(X + (long)u[q]*PIN + li*8);
      #pragma unroll
      for (int q = 0; q < 4; q++)
        #pragma unroll
        for (int i = 0; i < 8; i++)
          acc[i] += wt[q]*(float)rows[q][i];
    }
    #pragma unroll
    for (int g = 1; g < G; g++)
      #pragma unroll
      for (int i = 0; i < 8; i++)
        acc[i] += __shfl(acc[i], lane + g*LPG, 64);
    int row = w*4 + q4;
    if (lane < LPG){
      bf16x8 o;
      #pragma unroll
      for (int i = 0; i < 8; i++) o[i] = (__bf16)acc[i];
      *(bf16x8*)(&lds[row*KPAD + lane*8]) = o;
    } else if (lane < KP/8){
      bf16x8 o = {};
      *(bf16x8*)(&lds[row*KPAD + lane*8]) = o;
    }
  }
  __syncthreads();

  // ---- phase 2: 32 x PHO GEMM from LDS; waves = 2 rowtiles x 4 coltiles ----
  int wrow = w & 1, wcol = w >> 1;
  int n0 = wcol*64;
  int ml = lane & 15, kq = lane >> 4;
  int m0 = wrow*16;
  f32x4 acc2[4] = {};
  if (n0 < PHO){
    const __bf16* Bp = Bt + (long)(n0 + ml)*KP + kq*8;
    #pragma unroll
    for (int k0 = 0; k0 < KP; k0 += 32){
      bf16x8 a = *(const bf16x8*)(&lds[(m0 + ml)*KPAD + kq*8 + k0]);
      #pragma unroll
      for (int t = 0; t < 4; t++){
        bf16x8 b = *(const bf16x8*)(Bp + (long)t*16*KP + k0);
        acc2[t] = __builtin_amdgcn_mfma_f32_16x16x32_bf16(a, b, acc2[t], 0, 0, 0);
      }
    }
  }
  __syncthreads();   // all As reads done; LDS reused for C staging
  if (n0 < PHO){
    const float inv = rsqrtf(1.0f + 1e-5f);
    int mr = m0 + kq*4;
    #pragma unroll
    for (int t = 0; t < 4; t++){
      int gn = n0 + t*16 + ml;
      if (gn >= PHO) continue;
      bool real = gn < N;
      float gbb = real ? gb[gn] : 0.f;
      float sc  = real ? bng[gn]*inv : 0.f;
      float bb_ = real ? bnb[gn] : 0.f;
      #pragma unroll
      for (int r = 0; r < 4; r++){
        float xg = real ? fast_tanh((acc2[t][r] + gbb)*sc + bb_) : 0.f;
        lds[(mr + r)*PHO + gn] = (__bf16)xg;
      }
    }
  }
  __syncthreads();
  // coalesced copy-out: full bf16x8 rows
  for (int c = tid; c < 32*(PHO/8); c += 512){
    int row = c / (PHO/8), c8 = c - row*(PHO/8);
    *(bf16x8*)(C + (long)(vbase + row)*PHO + c8*8) =
        *(const bf16x8*)(&lds[row*PHO + c8*8]);
  }
}

// ---------------- bf16 MFMA GEMM, fp32 out (pred) ----------------

template<int KP, int ACT, int WPB>
__global__ __launch_bounds__(WPB*64) void mfma_gemm(
    const __bf16* __restrict__ A, const __bf16* __restrict__ Bt,
    float* __restrict__ C, long ldc, int M, int N)
{
  int w = threadIdx.x >> 6, l = threadIdx.x & 63;
  int m0 = blockIdx.y*(WPB*16) + w*16;
  int n0 = blockIdx.x*64;
  int ml = l & 15, kq = l >> 4;
  const __bf16* Ap = A  + (long)(m0 + ml)*KP + kq*8;
  const __bf16* Bp = Bt + (long)(n0 + ml)*KP + kq*8;
  f32x4 acc[4] = {};
  #pragma unroll
  for (int k0 = 0; k0 < KP; k0 += 32){
    bf16x8 a = *(const bf16x8*)(Ap + k0);
    #pragma unroll
    for (int t = 0; t < 4; t++){
      bf16x8 b = *(const bf16x8*)(Bp + (long)t*16*KP + k0);
      acc[t] = __builtin_amdgcn_mfma_f32_16x16x32_bf16(a, b, acc[t], 0, 0, 0);
    }
  }
  int mr = m0 + kq*4;
  #pragma unroll
  for (int t = 0; t < 4; t++){
    int gn = n0 + t*16 + ml;
    if (gn >= N) continue;
    #pragma unroll
    for (int r = 0; r < 4; r++){
      int gm = mr + r;
      if (gm < M){
        float x = acc[t][r];
        if (ACT == 2) x = 1.f/(1.f + __expf(-x));
        C[(long)gm*ldc + gn] = x;
      }
    }
  }
}

// ---------------- fc MFMA: split-K, atomic accumulate ----------------

__global__ __launch_bounds__(256) void mfma_fc_k(
    const __bf16* __restrict__ A, const __bf16* __restrict__ Bt,
    float* __restrict__ C, int M, int N, int klen)
{
  int w = threadIdx.x >> 6, l = threadIdx.x & 63;
  int m0 = blockIdx.y*64 + w*16;
  int n0 = blockIdx.x*128;
  long kb = (long)blockIdx.z * klen;
  int ml = l & 15, kq = l >> 4;
  const __bf16* Ap = A  + (long)(m0 + ml)*FCK + kb + kq*8;
  const __bf16* Bp = Bt + (long)(n0 + ml)*FCK + kb + kq*8;
  f32x4 acc[2][4] = {};
  #pragma unroll 2
  for (int k0 = 0; k0 < klen; k0 += 32){
    bf16x8 a = *(const bf16x8*)(Ap + k0);
    #pragma unroll
    for (int c = 0; c < 2; c++)
      #pragma unroll
      for (int t = 0; t < 4; t++){
        bf16x8 b = *(const bf16x8*)(Bp + (long)(c*64 + t*16)*FCK + k0);
        acc[c][t] = __builtin_amdgcn_mfma_f32_16x16x32_bf16(a, b, acc[c][t], 0, 0, 0);
      }
  }
  int mr = m0 + kq*4;
  #pragma unroll
  for (int c = 0; c < 2; c++)
    #pragma unroll
    for (int t = 0; t < 4; t++){
      int gn = n0 + c*64 + t*16 + ml;
      if (gn >= N) continue;
      #pragma unroll
      for (int r = 0; r < 4; r++){
        int gm = mr + r;
        if (gm < M) atomicAdd(&C[(long)gm*N + gn], acc[c][t][r]);
      }
    }
}

// ---------------- head MFMA: direct-load hi/lo bf16 split GEMM ----------------

template<int NPROD, int COMBINE, bool SPLITOUT>
__global__ __launch_bounds__(256) void mfma_head_k(
    const __bf16* __restrict__ A0, const __bf16* __restrict__ B0,
    const __bf16* __restrict__ A1, const __bf16* __restrict__ B1,
    const float* __restrict__ bias0, const float* __restrict__ bias1,
    float* __restrict__ outF, __bf16* __restrict__ outS,
    int ldc, int N)
{
  int w = threadIdx.x >> 6, l = threadIdx.x & 63;
  int m0 = blockIdx.y*64 + w*16;
  int n0 = blockIdx.x*64;
  int ml = l & 15, kq = l >> 4;
  long aoff = (long)(m0 + ml)*KPP + kq*8;
  long boff = (long)(n0 + ml)*KPP + kq*8;
  f32x4 accA[4] = {}, accB[4] = {};
  #pragma unroll
  for (int k0 = 0; k0 < KPP; k0 += 32){
    bf16x8 ah = *(const bf16x8*)(A0 + aoff + k0);
    bf16x8 al = *(const bf16x8*)(A0 + ALO + aoff + k0);
    #pragma unroll
    for (int t = 0; t < 4; t++){
      bf16x8 bh = *(const bf16x8*)(B0 + boff + (long)t*16*KPP + k0);
      bf16x8 bl = *(const bf16x8*)(B0 + BLO + boff + (long)t*16*KPP + k0);
      accA[t] = __builtin_amdgcn_mfma_f32_16x16x32_bf16(ah, bh, accA[t], 0, 0, 0);
      accA[t] = __builtin_amdgcn_mfma_f32_16x16x32_bf16(al, bh, accA[t], 0, 0, 0);
      accA[t] = __builtin_amdgcn_mfma_f32_16x16x32_bf16(ah, bl, accA[t], 0, 0, 0);
    }
    if constexpr (NPROD == 2){
      bf16x8 ch = *(const bf16x8*)(A1 + aoff + k0);
      bf16x8 cl = *(const bf16x8*)(A1 + ALO + aoff + k0);
      #pragma unroll
      for (int t = 0; t < 4; t++){
        bf16x8 bh = *(const bf16x8*)(B1 + boff + (long)t*16*KPP + k0);
        bf16x8 bl = *(const bf16x8*)(B1 + BLO + boff + (long)t*16*KPP + k0);
        accB[t] = __builtin_amdgcn_mfma_f32_16x16x32_bf16(ch, bh, accB[t], 0, 0, 0);
        accB[t] = __builtin_amdgcn_mfma_f32_16x16x32_bf16(cl, bh, accB[t], 0, 0, 0);
        accB[t] = __builtin_amdgcn_mfma_f32_16x16x32_bf16(ch, bl, accB[t], 0, 0, 0);
      }
    }
  }
  int mr = m0 + kq*4;
  #pragma unroll
  for (int t = 0; t < 4; t++){
    int gn = n0 + t*16 + ml;
    if (SPLITOUT){ if (gn >= KPP) continue; }
    else         { if (gn >= N)   continue; }
    bool real = gn < N;
    float bb0 = real ? bias0[gn] : 0.f;
    float bb1 = (COMBINE == 0 && real) ? bias1[gn] : 0.f;
    #pragma unroll
    for (int r = 0; r < 4; r++){
      int gm = mr + r;
      float x;
      if (COMBINE == 0){
        float xa = accA[t][r] + bb0; xa = (xa >= 0.f) ? xa : 0.01f*xa;
        float xb = accB[t][r] + bb1; xb = (xb >= 0.f) ? xb : 0.01f*xb;
        x = xa + xb;
      } else if (COMBINE == 1){
        x = accA[t][r] + accB[t][r] + bb0;
        x = (x >= 0.f) ? x : 0.01f*x;
      } else {
        x = accA[t][r] + bb0;
        x = 1.f/(1.f + __expf(-x));
      }
      if (!real) x = 0.f;
      if (SPLITOUT){
        __bf16 h = (__bf16)x;
        outS[(long)gm*KPP + gn] = h;
        outS[ALO + (long)gm*KPP + gn] = (__bf16)(x - (float)h);
      } else {
        outF[(long)gm*ldc + gn] = x;
      }
    }
  }
}

// ---------------- conversion helpers ----------------

__global__ __launch_bounds__(256) void emb_to_bf16_k(const float* __restrict__ src,
                                                     __bf16* __restrict__ dst){
  int lane = threadIdx.x & 63;
  int half = lane >> 5, l = lane & 31;
  long r = (long)blockIdx.x*8 + (threadIdx.x >> 6)*2 + half;
  if (r >= NNODES || l >= 26) return;
  float4 v = make_float4(0.f, 0.f, 0.f, 0.f);
  if (l < 25) v = *(const float4*)(src + r*INIT_F + l*4);
  __bf16 o[4] __attribute__((aligned(8))) =
      {(__bf16)v.x, (__bf16)v.y, (__bf16)v.z, (__bf16)v.w};
  *reinterpret_cast<uint2*>(dst + r*KPE + l*4) = *reinterpret_cast<const uint2*>(o);
}

__global__ void transpose_w_k(const float* __restrict__ W, __bf16* __restrict__ Bt,
                              int K, int N, int Kp){
  int n = blockIdx.x;
  for (int k = threadIdx.x; k < Kp; k += blockDim.x){
    float v = (k < K && n < N) ? W[(long)k*N + n] : 0.f;
    Bt[(long)n*Kp + k] = (__bf16)v;
  }
}

__global__ void f32_to_bf16_flat_k(const float4* __restrict__ src,
                                   __bf16* __restrict__ dst, long n4){
  long i = (long)blockIdx.x*256 + threadIdx.x;
  if (i >= n4) return;
  float4 v = src[i];
  __bf16 o[4] __attribute__((aligned(8))) =
      {(__bf16)v.x, (__bf16)v.y, (__bf16)v.z, (__bf16)v.w};
  *reinterpret_cast<uint2*>(dst + i*4) = *reinterpret_cast<const uint2*>(o);
}

// Split the 5 head weight matrices into bf16 hi/lo Bt form [mat][2][256][KPP].
__global__ void head_wsplit_k(const float* __restrict__ bi, const float* __restrict__ si,
                              const float* __restrict__ cs, const float* __restrict__ fc2,
                              __bf16* __restrict__ W){
  int k = threadIdx.x; if (k >= KPP) return;
  int n = blockIdx.x;            // 0..255
  int mat = blockIdx.y;          // 0..4
  float v = 0.f;
  if (k < D_F){
    if      (mat == 0){ if (n < D_F) v = bi[(long)n*D_F + k]; }
    else if (mat == 1){ if (n < D_F) v = si[(long)n*D_F + k]; }
    else if (mat == 2){ if (n < D_F) v = cs[(long)n*2*D_F + k]; }
    else if (mat == 3){ if (n < D_F) v = cs[(long)n*2*D_F + D_F + k]; }
    else              { if (n < NCL) v = fc2[(long)n*D_F + k]; }
  }
  __bf16 h = (__bf16)v;
  long base = (long)mat*2*BLO + (long)n*KPP + k;
  W[base]       = h;
  W[base + BLO] = (__bf16)(v - (float)h);
}

// ---------------- small fused kernels ----------------

__global__ void conv_bn_relu_k(const int* __restrict__ e1, const int* __restrict__ rel,
                               const __bf16* __restrict__ AEh, const float* __restrict__ embrel,
                               const float* __restrict__ g0, const float* __restrict__ b0,
                               const float* __restrict__ cw, const float* __restrict__ cb,
                               const float* __restrict__ g1, const float* __restrict__ b1,
                               __bf16* __restrict__ out){
  __shared__ float sh[2][D_F];
  int b = blockIdx.y, c0 = blockIdx.x*8, t = threadIdx.x;
  const float inv = rsqrtf(1.0f + 1e-5f);
  if (t < D_F){
    sh[0][t] = (float)AEh[(long)e1[b]*KPP + t] * (g0[0]*inv) + b0[0];
    sh[1][t] = embrel[(long)rel[b]*D_F + t]    * (g0[1]*inv) + b0[1];
  }
  __syncthreads();
  if (t >= D_F) return;
  for (int cc = 0; cc < 8; cc++){
    int c = c0 + cc;
    float sum = cb[c];
    #pragma unroll
    for (int i = 0; i < 2; i++){
      #pragma unroll
      for (int k = 0; k < 5; k++){
        int h = t + k - 2;
        float sv = (h >= 0 && h < D_F) ? sh[i][h] : 0.f;
        sum += sv * cw[(c*2+i)*5 + k];
      }
    }
    float x = sum * (g1[c]*inv) + b1[c];
    out[((long)b*CCH + c)*D_F + t] = (__bf16)fmaxf(x, 0.f);
  }
}

__global__ void fc_fin_k(const float* __restrict__ raw, const float* __restrict__ fb,
                         const float* __restrict__ g, const float* __restrict__ bb,
                         __bf16* __restrict__ x2s){
  int b = blockIdx.x, t = threadIdx.x;
  if (t >= KPP) return;
  float x = 0.f;
  if (t < D_F){
    const float inv = rsqrtf(1.0f + 1e-5f);
    x = (raw[b*D_F + t] + fb[t]) * (g[t]*inv) + bb[t];
    x = fmaxf(x, 0.f);
  }
  __bf16 h = (__bf16)x;
  x2s[(long)b*KPP + t] = h;
  x2s[ALO + (long)b*KPP + t] = (__bf16)(x - (float)h);
}

__global__ void feats_k(const int* __restrict__ attr, const __bf16* __restrict__ AEh,
                        __bf16* __restrict__ hA){
  int b = blockIdx.x, t = threadIdx.x;
  if (t >= KPP) return;
  float s = 0.f, sq = 0.f;
  if (t < D_F){
    #pragma unroll
    for (int a = 0; a < NA_; a++){
      int id = attr[b*NA_ + a];
      float v = (float)AEh[(long)id*KPP + t];
      s += v; sq += v*v;
    }
  }
  float dp = 0.5f*(s*s - sq);
  long o = (long)b*KPP + t;
  __bf16 hd = (__bf16)dp;
  hA[o]            = hd;
  hA[o + ALO]      = (__bf16)(dp - (float)hd);
  __bf16 hs = (__bf16)s;
  hA[o + 2*ALO]    = hs;
  hA[o + 3*ALO]    = (__bf16)(s - (float)hs);
}

// ---------------- launch ----------------

extern "C" void kernel_launch(void* const* d_in, const int* in_sizes, int n_in,
                              void* d_out, int out_size, void* d_ws, size_t ws_size,
                              hipStream_t stream) {
  const int* e1       = (const int*)d_in[0];
  const int* rel      = (const int*)d_in[1];
  const int* attr     = (const int*)d_in[2];
  const int* ei       = (const int*)d_in[4];
  const int* erel     = (const int*)d_in[5];
  const float* emb_e  = (const float*)d_in[6];
  const float* embrel = (const float*)d_in[7];
  const float* alpha1 = (const float*)d_in[8];
  const float* alpha2 = (const float*)d_in[9];
  const float* gc1_W  = (const float*)d_in[10];
  const float* gc1_b  = (const float*)d_in[11];
  const float* gc2_W  = (const float*)d_in[12];
  const float* gc2_b  = (const float*)d_in[13];
  const float* bn3_g  = (const float*)d_in[14];
  const float* bn3_b  = (const float*)d_in[15];
  const float* bn4_g  = (const float*)d_in[16];
  const float* bn4_b  = (const float*)d_in[17];
  const float* bn0_g  = (const float*)d_in[18];
  const float* bn0_b  = (const float*)d_in[19];
  const float* conv_w = (const float*)d_in[20];
  const float* conv_b = (const float*)d_in[21];
  const float* bn1_g  = (const float*)d_in[22];
  const float* bn1_b  = (const float*)d_in[23];
  const float* fc_w   = (const float*)d_in[24];
  const float* fc_b   = (const float*)d_in[25];
  const float* bn2_g  = (const float*)d_in[26];
  const float* bn2_b  = (const float*)d_in[27];
  const float* bi_w   = (const float*)d_in[28];
  const float* bi_b   = (const float*)d_in[29];
  const float* si_w   = (const float*)d_in[30];
  const float* si_b   = (const float*)d_in[31];
  const float* cs_w   = (const float*)d_in[32];
  const float* cs_b   = (const float*)d_in[33];
  const float* fc2_w  = (const float*)d_in[34];
  const float* fc2_b  = (const float*)d_in[35];

  float* pred_out = (float*)d_out;                       // 128 x 100000
  float* clus_out = (float*)d_out + (long)BB*NNODES;     // 128 x 16

  char* w = (char*)d_ws;
  size_t off = 0;
  auto alloc = [&](size_t bytes) -> void* {
    off = (off + 255) & ~(size_t)255;
    void* p = w + off;
    off += bytes;
    return p;
  };
  __bf16* AEh  = (__bf16*)alloc((size_t)MROWS*KPP*2);   // 44.8 MB, final embeddings
  void* bufA   = alloc((size_t)MROWS*KPE*2);            // emb_h (20.8MB) / fcBt (20.5MB)
  void* bufB   = alloc((size_t)BB*FCK*2);               // convout (10.3MB)
  __bf16* H1h  = (__bf16*)alloc((size_t)MROWS*KP2*2);   // 32 MB

  int* bcur   = (int*)alloc((size_t)NBUK*4);
  int* start_ = (int*)alloc((size_t)NNODES*4);
  int* deg    = (int*)alloc((size_t)NNODES*4);
  int2* blist = (int2*)alloc((size_t)NBUK*BCAP*8);      // 12.8 MB
  unsigned* adjW = (unsigned*)alloc((size_t)NBUK*BCAP*4); // 6.4 MB
  __bf16* Bt1 = (__bf16*)alloc((size_t)256*KP1*2);      // 256 rows, zero-padded
  __bf16* Bt2 = (__bf16*)alloc((size_t)256*KP2*2);
  __bf16* headW = (__bf16*)alloc((size_t)5*2*256*KPP*2);   // 1.15 MB
  __bf16* headA = (__bf16*)alloc((size_t)5*2*128*KPP*2);   // 0.57 MB
  float* x2raw  = (float*)alloc((size_t)BB*D_F*4);

  __bf16* emb_h   = (__bf16*)bufA;   // pitch 104
  __bf16* fcBt    = (__bf16*)bufA;   // 256 x 40000 (emb_h dead after layer 1)
  __bf16* convout = (__bf16*)bufB;   // 128 x 40000

  auto HAp = [&](int slot){ return headA + (size_t)slot*2*ALO; };
  auto HWp = [&](int mat){ return headW + (size_t)mat*2*BLO; };

  const int MT = MROWS/64;        // 1563
  const int MT32 = NNODES/32;     // 3125 (exact)

  // ---- bucketed CSR build ----
  hipMemsetAsync(bcur, 0, (size_t)NBUK*4, stream);
  hipMemsetAsync(x2raw, 0, (size_t)BB*D_F*4, stream);
  bucket_a_k<<<(EDG + 1023)/1024, 256, 0, stream>>>(ei, erel, bcur, blist);
  bucket_b_k<<<NBUK, 256, 0, stream>>>(blist, bcur, adjW, start_, deg);

  // ---- operand prep ----
  emb_to_bf16_k<<<(NNODES + 7)/8, 256, 0, stream>>>(emb_e, emb_h);
  transpose_w_k<<<256, 128, 0, stream>>>(gc1_W, Bt1, INIT_F, GC1_F, KP1);
  transpose_w_k<<<256, 128, 0, stream>>>(gc2_W, Bt2, GC1_F, D_F, KP2);
  head_wsplit_k<<<dim3(256,5), 256, 0, stream>>>(bi_w, si_w, cs_w, fc2_w, headW);

  // ---- GCN layer 1 (fused gather + GEMM): H1h = tanh(bn3(agg(emb_h)@W1 + b1)) ----
  gcn_layer_k<4,13,KPE,KP1,KP2><<<MT32, 512, 0, stream>>>(
      emb_h, start_, deg, adjW, alpha1, Bt1, H1h, gc1_b, bn3_g, bn3_b, GC1_F);

  // ---- GCN layer 2 (fused): AEh = tanh(bn4(agg(H1h)@W2 + b2)) ----
  gcn_layer_k<3,20,KP2,KP2,KPP><<<MT32, 512, 0, stream>>>(
      H1h, start_, deg, adjW, alpha2, Bt2, AEh, gc2_b, bn4_g, bn4_b, D_F);

  // ---- conv head (convout emitted as bf16 fc A-operand) ----
  {
    dim3 grid(CCH/8, BB);
    conv_bn_relu_k<<<grid, 256, 0, stream>>>(e1, rel, AEh, embrel, bn0_g, bn0_b,
                                             conv_w, conv_b, bn1_g, bn1_b, convout);
  }
  {
    long n4 = (long)D_F*FCK/4;   // 2,000,000
    f32_to_bf16_flat_k<<<(int)((n4 + 255)/256), 256, 0, stream>>>(
        (const float4*)fc_w, fcBt, n4);
  }
  {
    dim3 grid(2, 2, 125);
    mfma_fc_k<<<grid, 256, 0, stream>>>(convout, fcBt, x2raw, BB, D_F, 320);
  }
  fc_fin_k<<<BB, 256, 0, stream>>>(x2raw, fc_b, bn2_g, bn2_b, HAp(2));

  // ---- NFM branch (direct-load hi/lo MFMA) ----
  feats_k<<<BB, 256, 0, stream>>>(attr, AEh, headA);
  {
    dim3 grid(4, 2);
    // nfm(slot3) = lrelu(deep@bi^T + bi_b) + lrelu(ssum@si^T + si_b)
    mfma_head_k<2,0,true><<<grid, 256, 0, stream>>>(
        HAp(0), HWp(0), HAp(1), HWp(1), bi_b, si_b, nullptr, HAp(3), 0, D_F);
    // userb(slot4) = lrelu(nfm@cs1^T + x2@cs2^T + cs_b)
    mfma_head_k<2,1,true><<<grid, 256, 0, stream>>>(
        HAp(3), HWp(2), HAp(2), HWp(3), cs_b, nullptr, nullptr, HAp(4), 0, D_F);
  }

  // ---- outputs ----
  {
    // pred = sigmoid(userb_hi @ AEh^T) : M=128, N=100000; AEh read once.
    // AEh rows 100000..100031 are unwritten garbage: they feed only masked
    // output columns (gn >= N), each with its own accumulator -> safe.
    dim3 grid(MT, 1);
    mfma_gemm<KPP,2,8><<<grid, 512, 0, stream>>>(HAp(4), AEh, pred_out, NNODES, BB, NNODES);
  }
  {
    // clusters = sigmoid(userb @ fc2_w^T + fc2_b) : M=128, N=16 (hi/lo MFMA)
    dim3 grid(1, 2);
    mfma_head_k<1,2,false><<<grid, 256, 0, stream>>>(
        HAp(4), HWp(4), nullptr, nullptr, fc2_b, nullptr, clus_out, nullptr, NCL, NCL);
  }
}